// Round 8
// baseline (114.621 us; speedup 1.0000x reference)
//
#include <hip/hip_runtime.h>
#include <hip/hip_fp16.h>

#define BB 8
#define CC 3
#define HH 720
#define WW 1280
#define PLANE (HH*WW)
#define NPIX (BB*HH*WW)

#define PXX 64              // output tile width per block
#define PYY 16              // output tile height per block
#define RAD 3               // regular iff flow in [-3,3) per axis
#define NBX (WW/PXX)        // 20
#define NBY (HH/PYY)        // 45
#define NBLK (BB*NBY*NBX)   // 7200
#define WINX (PXX+2*RAD)    // 70
#define WINY (PYY+2*RAD)    // 22
#define NWIN (WINX*WINY)    // 1540
#define CX 65               // corner cells x: x0 in [X0-1, X0+63]
#define CY (PYY+1)          // 17: y0 in [Y0-1, Y0+15]
#define NCELL (CX*CY)       // 1105
#define DEPTH 4
#define THREADS 512
#define NBATCH 4            // ceil(1540/512); 4th batch has 4 active items
#define OVF_CAP 64          // per-block overflow slab slots

// LDS layout in dwords: FXY | V01 | V2(half) | CNT | lovf = 48624 bytes
#define OFF_FXY 0
#define OFF_V01 (NCELL*DEPTH)                    // 4420
#define OFF_V2  (2*NCELL*DEPTH)                  // 8840
#define OFF_CNT (2*NCELL*DEPTH + NCELL*DEPTH/2)  // 11050
#define OFF_LOVF (OFF_CNT + NCELL)               // 12155
#define LDS_DW  (OFF_LOVF + 1)                   // 12156 (= 3039 uint4 exactly)

static __device__ __forceinline__ float h2f_lo(unsigned int u) {
    return __half2float(__ushort_as_half((unsigned short)(u & 0xffffu)));
}
static __device__ __forceinline__ float h2f_hi(unsigned int u) {
    return __half2float(__ushort_as_half((unsigned short)(u >> 16)));
}

// ---------------------------------------------------------------------------
// main kernel: bucket records by corner cell in LDS; x-pair register gather
// ---------------------------------------------------------------------------
__global__ __launch_bounds__(THREADS, 6) void fw_gather(
    const float* __restrict__ im0,
    const float* __restrict__ flow,
    float* __restrict__ out,
    unsigned int* __restrict__ cnt_g,      // [NBLK]
    float* __restrict__ ovf_rec)           // [NBLK*OVF_CAP*6]
{
    __shared__ __align__(16) unsigned int lds[LDS_DW];
    unsigned int* FXY = lds + OFF_FXY;
    unsigned int* V01 = lds + OFF_V01;
    unsigned short* V2h = (unsigned short*)(lds + OFF_V2);
    unsigned int* CNT = lds + OFF_CNT;
    unsigned int* LOVF = lds + OFF_LOVF;

    // XCD-chunked swizzle: 7200 = 8*900; XCD k owns batch image k contiguously
    const int phys = blockIdx.x;
    const int virt = (phys & 7) * (NBLK / 8) + (phys >> 3);
    const int b  = virt / (NBX * NBY);
    int r2 = virt - b * (NBX * NBY);
    const int by = r2 / NBX;
    const int bx = r2 - by * NBX;
    const int X0 = bx * PXX, Y0 = by * PYY;
    const int tid = threadIdx.x;

    // ---- prefetch: issue loads before anything depends on them (MLP) ----
    float2 fv[NBATCH];
    float pv0[NBATCH], pv1[NBATCH], pv2[NBATCH];
    int pgx[NBATCH], pgy[NBATCH];
    bool pok[NBATCH];
#pragma unroll
    for (int t = 0; t < NBATCH; ++t) {
        int i = tid + t * THREADS;
        int wy = i / WINX;
        int wx = i - wy * WINX;
        int gx = X0 - RAD + wx;
        int gy = Y0 - RAD + wy;
        pok[t] = (i < NWIN) & (gx >= 0) & (gx < WW) & (gy >= 0) & (gy < HH);
        pgx[t] = gx; pgy[t] = gy;
        if (t < NBATCH - 1 || i < NWIN) {   // t<3 folds to unconditional
            int cgx = min(max(gx, 0), WW - 1);
            int cgy = min(max(gy, 0), HH - 1);
            fv[t] = reinterpret_cast<const float2*>(flow)[(b * HH + cgy) * WW + cgx];
            int src = b * CC * PLANE + cgy * WW + cgx;
            pv0[t] = im0[src];
            pv1[t] = im0[src + PLANE];
            pv2[t] = im0[src + 2 * PLANE];
        } else {
            fv[t] = make_float2(0.f, 0.f);
            pv0[t] = 0.f; pv1[t] = 0.f; pv2[t] = 0.f;
        }
    }

    // zero LDS while loads are in flight (zero slots contribute exactly 0)
    uint4* lds4 = reinterpret_cast<uint4*>(lds);
    for (int i = tid; i < LDS_DW / 4; i += THREADS)
        lds4[i] = make_uint4(0u, 0u, 0u, 0u);
    __syncthreads();

    // ---- phase A: bucket records from registers ----
#pragma unroll
    for (int t = 0; t < NBATCH; ++t) {
        if (!pok[t]) continue;
        float2 f = fv[t];
        int gx = pgx[t], gy = pgy[t];
        bool reg = (f.x >= -(float)RAD) & (f.x < (float)RAD)
                 & (f.y >= -(float)RAD) & (f.y < (float)RAD);
        if (reg) {
            float x = (float)gx + f.x;       // same op order as reference
            float y = (float)gy + f.y;
            float x0f = floorf(x), y0f = floorf(y);
            int cx = (int)x0f - (X0 - 1);
            int cy = (int)y0f - (Y0 - 1);
            if (cx >= 0 && cx < CX && cy >= 0 && cy < CY) {
                float fx = x - x0f, fy = y - y0f;
                int cell = cy * CX + cx;
                unsigned int slot = atomicAdd(&CNT[cell], 1u);
                if (slot < DEPTH) {
                    int o = cell * DEPTH + slot;
                    FXY[o] = (unsigned int)__half_as_ushort(__float2half(fx))
                           | ((unsigned int)__half_as_ushort(__float2half(fy)) << 16);
                    V01[o] = (unsigned int)__half_as_ushort(__float2half(pv0[t]))
                           | ((unsigned int)__half_as_ushort(__float2half(pv1[t])) << 16);
                    V2h[o] = __half_as_ushort(__float2half(pv2[t]));
                } else {
                    // depth overflow (rare): owner-clipped replay (type 1)
                    unsigned int s2 = atomicAdd(LOVF, 1u);
                    if (s2 < OVF_CAP) {
                        float* q = ovf_rec + ((size_t)phys * OVF_CAP + s2) * 6;
                        q[0] = __int_as_float(b | (bx << 4) | (by << 9) | (1 << 16));
                        q[1] = x; q[2] = y;
                        q[3] = pv0[t]; q[4] = pv1[t]; q[5] = pv2[t];
                    }
                }
            }
        } else {
            int wx = gx - (X0 - RAD);
            int wy = gy - (Y0 - RAD);
            if (wx >= RAD && wx < RAD + PXX && wy >= RAD && wy < RAD + PYY) {
                // irregular flow, core-owned pixel: full-splat replay (type 0)
                unsigned int s2 = atomicAdd(LOVF, 1u);
                if (s2 < OVF_CAP) {
                    float* q = ovf_rec + ((size_t)phys * OVF_CAP + s2) * 6;
                    q[0] = __int_as_float(b | (bx << 4) | (by << 9));
                    q[1] = (float)gx + f.x; q[2] = (float)gy + f.y;
                    q[3] = pv0[t]; q[4] = pv1[t]; q[5] = pv2[t];
                }
            }
        }
    }
    __syncthreads();

    if (tid == 0) cnt_g[phys] = min(*LOVF, (unsigned int)OVF_CAP);

    // ---- phase B: x-pair gather, 2 outputs/thread from 6 cells ----
    const int pcol = tid & 31;                 // pair column 0..31
    const int wrow = tid >> 5;                 // row 0..15
    const int X = X0 + 2 * pcol;               // outputs X (A) and X+1 (B)
    const int Y = Y0 + wrow;

    float aA0 = 0.f, aA1 = 0.f, aA2 = 0.f;
    float aB0 = 0.f, aB1 = 0.f, aB2 = 0.f;

#pragma unroll
    for (int r = 0; r < 2; ++r) {              // cell row y0 = Y-1+r
        const int cy = wrow + r;
#pragma unroll
        for (int t = 0; t < 3; ++t) {          // cell cols x0 = X-1, X, X+1
            const int cell = (cy * CX + 2 * pcol + t) * DEPTH;
            uint4 fxy4 = *reinterpret_cast<const uint4*>(&FXY[cell]);
            uint4 v014 = *reinterpret_cast<const uint4*>(&V01[cell]);
            ushort4 v24 = *reinterpret_cast<const ushort4*>(&V2h[cell]);
            unsigned int fxys[4] = {fxy4.x, fxy4.y, fxy4.z, fxy4.w};
            unsigned int v01s[4] = {v014.x, v014.y, v014.z, v014.w};
            unsigned short v2s[4] = {v24.x, v24.y, v24.z, v24.w};
#pragma unroll
            for (int k = 0; k < DEPTH; ++k) {
                float fx = h2f_lo(fxys[k]);
                float fy = h2f_hi(fxys[k]);
                float wyv = r ? (1.0f - fy) : fy;   // y0=Y-1: fy; y0=Y: 1-fy
                float v0 = h2f_lo(v01s[k]);
                float v1 = h2f_hi(v01s[k]);
                float v2 = __half2float(__ushort_as_half(v2s[k]));
                if (t == 0) {                  // x0 = X-1 -> A with weight fx
                    float wt = fx * wyv;
                    aA0 += wt * v0; aA1 += wt * v1; aA2 += wt * v2;
                } else if (t == 1) {           // x0 = X -> A:(1-fx), B:fx
                    float wtA = (1.0f - fx) * wyv;
                    float wtB = fx * wyv;
                    aA0 += wtA * v0; aA1 += wtA * v1; aA2 += wtA * v2;
                    aB0 += wtB * v0; aB1 += wtB * v1; aB2 += wtB * v2;
                } else {                       // x0 = X+1 -> B with weight 1-fx
                    float wt = (1.0f - fx) * wyv;
                    aB0 += wt * v0; aB1 += wt * v1; aB2 += wt * v2;
                }
            }
        }
    }

    size_t o = (size_t)(b * CC) * PLANE + (size_t)Y * WW + X;
    *reinterpret_cast<float2*>(&out[o])             = make_float2(aA0, aB0);
    *reinterpret_cast<float2*>(&out[o + PLANE])     = make_float2(aA1, aB1);
    *reinterpret_cast<float2*>(&out[o + 2 * PLANE]) = make_float2(aA2, aB2);
}

// ---------------------------------------------------------------------------
// replay: scan per-block slabs. type0 = full splat, type1 = owner-clipped
// ---------------------------------------------------------------------------
__global__ __launch_bounds__(256) void fw_overflow(
    const unsigned int* __restrict__ cnt_g,
    const float* __restrict__ ovf_rec,
    float* __restrict__ out)
{
    int i = blockIdx.x * 256 + threadIdx.x;    // global slot id
    if (i >= NBLK * OVF_CAP) return;
    int blk  = i / OVF_CAP;
    int slot = i - blk * OVF_CAP;
    if ((unsigned int)slot >= cnt_g[blk]) return;

    const float* q = ovf_rec + (size_t)i * 6;
    unsigned int meta = __float_as_uint(q[0]);
    int b   = meta & 0xf;
    int rx0 = ((meta >> 4) & 0x1f) * PXX;
    int ry0 = ((meta >> 9) & 0x7f) * PYY;
    int typ = (meta >> 16) & 1;
    float x = q[1], y = q[2];
    float v0 = q[3], v1 = q[4], v2 = q[5];
    float x0f = floorf(x), y0f = floorf(y);
    int x0 = (int)x0f, y0 = (int)y0f;
    float wx1 = x - x0f, wx0 = 1.0f - wx1;
    float wy1 = y - y0f, wy0 = 1.0f - wy1;
#pragma unroll
    for (int dy = 0; dy < 2; ++dy) {
        int yi = y0 + dy;
        float wy = dy ? wy1 : wy0;
#pragma unroll
        for (int dx = 0; dx < 2; ++dx) {
            int xi = x0 + dx;
            bool valid = (xi >= 0) && (xi < WW) && (yi >= 0) && (yi < HH);
            if (typ)
                valid = valid && (xi >= rx0) && (xi < rx0 + PXX)
                              && (yi >= ry0) && (yi < ry0 + PYY);
            if (valid) {
                float wt = wy * (dx ? wx1 : wx0);
                int o = b * CC * PLANE + yi * WW + xi;
                unsafeAtomicAdd(&out[o],             wt * v0);
                unsafeAtomicAdd(&out[o + PLANE],     wt * v1);
                unsafeAtomicAdd(&out[o + 2 * PLANE], wt * v2);
            }
        }
    }
}

// ---------------------------------------------------------------------------
// safety fallback (tiny ws): naive global-atomic splat
// ---------------------------------------------------------------------------
__global__ __launch_bounds__(256) void fw_naive(
    const float* __restrict__ im0,
    const float* __restrict__ flow,
    float* __restrict__ out)
{
    int idx = blockIdx.x * blockDim.x + threadIdx.x;
    if (idx >= NPIX) return;
    int w = idx % WW;
    int t = idx / WW;
    int h = t % HH;
    int b = t / HH;
    float2 f = reinterpret_cast<const float2*>(flow)[idx];
    float x = (float)w + f.x, y = (float)h + f.y;
    float x0f = floorf(x), y0f = floorf(y);
    int x0 = (int)x0f, y0 = (int)y0f;
    float wx1 = x - x0f, wx0 = 1.0f - wx1;
    float wy1 = y - y0f, wy0 = 1.0f - wy1;
    int src = (b * CC * HH + h) * WW + w;
    float v0 = im0[src], v1 = im0[src + PLANE], v2 = im0[src + 2 * PLANE];
#pragma unroll
    for (int dy = 0; dy < 2; ++dy) {
        int yi = y0 + dy;
        if (yi < 0 || yi >= HH) continue;
        float wy = dy ? wy1 : wy0;
#pragma unroll
        for (int dx = 0; dx < 2; ++dx) {
            int xi = x0 + dx;
            if (xi < 0 || xi >= WW) continue;
            float wt = wy * (dx ? wx1 : wx0);
            int o = (b * CC) * PLANE + yi * WW + xi;
            unsafeAtomicAdd(&out[o],             wt * v0);
            unsafeAtomicAdd(&out[o + PLANE],     wt * v1);
            unsafeAtomicAdd(&out[o + 2 * PLANE], wt * v2);
        }
    }
}

extern "C" void kernel_launch(void* const* d_in, const int* in_sizes, int n_in,
                              void* d_out, int out_size, void* d_ws, size_t ws_size,
                              hipStream_t stream)
{
    const float* im0  = (const float*)d_in[0];
    const float* flow = (const float*)d_in[1];
    float* out = (float*)d_out;

    const size_t cnt_bytes = (size_t)NBLK * 4;                   // 28.8 KB
    const size_t rec_bytes = (size_t)NBLK * OVF_CAP * 24;        // ~11.1 MB
    if (ws_size >= cnt_bytes + rec_bytes) {
        unsigned int* cnt = (unsigned int*)d_ws;
        float* rec = (float*)((char*)d_ws + cnt_bytes);

        fw_gather<<<NBLK, THREADS, 0, stream>>>(im0, flow, out, cnt, rec);
        fw_overflow<<<(NBLK * OVF_CAP + 255) / 256, 256, 0, stream>>>(cnt, rec, out);
    } else {
        hipMemsetAsync(out, 0, (size_t)out_size * sizeof(float), stream);
        fw_naive<<<(NPIX + 255) / 256, 256, 0, stream>>>(im0, flow, out);
    }
}

// Round 9
// 88.714 us; speedup vs baseline: 1.2920x; 1.2920x over previous
//
#include <hip/hip_runtime.h>
#include <hip/hip_fp16.h>

#define BB 8
#define CC 3
#define HH 720
#define WW 1280
#define PLANE (HH*WW)
#define NPIX (BB*HH*WW)

#define PXX 64              // output tile width per block
#define PYY 8               // output tile height per block
#define RAD 3               // regular iff flow in [-3,3) per axis
#define NBX (WW/PXX)        // 20
#define NBY (HH/PYY)        // 90
#define NBLK (BB*NBY*NBX)   // 14400
#define WINX (PXX+2*RAD)    // 70
#define WINY (PYY+2*RAD)    // 14
#define NWIN (WINX*WINY)    // 980
#define CX 65               // corner cells x: x0 in [X0-1, X0+63]
#define CY (PYY+1)          // 9
#define NCELL (CX*CY)       // 585
#define DEPTH 4
#define THREADS 512
#define NBATCH 2            // ceil(980/512)
#define OVF_CAP 32          // per-block overflow slab slots (Poisson(~5) tail safe)

// Per-cell LDS layout, 56 bytes (14 dwords):
//   bytes  0..31 : WTT[4 corners][4 slots] f16  (corner c = dy*2+dx)
//   bytes 32..39 : V0[4 slots] f16
//   bytes 40..47 : V1[4 slots] f16
//   bytes 48..55 : V2[4 slots] f16
// 56B stride => lane-consecutive cells: each 16-lane group covers all 32
// banks exactly once on b64 reads (14 dw stride, gcd analysis) — conflict-free.
#define CELLB 56
#define OFF_CNT (NCELL*14)                   // dword offset of CNT[NCELL]
#define OFF_LOVF (OFF_CNT + NCELL)
#define LDS_DW  (OFF_LOVF + 2)               // 8778 dw (pad to even), 35112 B

typedef _Float16 hf2_t __attribute__((ext_vector_type(2)));

static __device__ __forceinline__ hf2_t as_h2(unsigned int u) {
    union { unsigned int u; hf2_t h; } c; c.u = u; return c.h;
}

#if defined(__has_builtin) && __has_builtin(__builtin_amdgcn_fdot2)
#define DOT2(w, v, acc) __builtin_amdgcn_fdot2((w), (v), (acc), false)
#else
static __device__ __forceinline__ float dot2_fallback(hf2_t w, hf2_t v, float acc) {
    return acc + (float)w.x * (float)v.x + (float)w.y * (float)v.y;
}
#define DOT2(w, v, acc) dot2_fallback((w), (v), (acc))
#endif

// ---------------------------------------------------------------------------
// main kernel: bucket records w/ precomputed corner weights; dot2 gather
// ---------------------------------------------------------------------------
__global__ __launch_bounds__(THREADS) void fw_gather(
    const float* __restrict__ im0,
    const float* __restrict__ flow,
    float* __restrict__ out,
    unsigned int* __restrict__ cnt_g,      // [NBLK]
    float* __restrict__ ovf_rec)           // [NBLK*OVF_CAP*6]
{
    __shared__ __align__(16) unsigned int lds[LDS_DW];
    unsigned int* CNT = lds + OFF_CNT;
    unsigned int* LOVF = lds + OFF_LOVF;

    // XCD-chunked swizzle: 14400 = 8*1800
    const int phys = blockIdx.x;
    const int virt = (phys & 7) * (NBLK / 8) + (phys >> 3);
    const int b  = virt / (NBX * NBY);
    int r2 = virt - b * (NBX * NBY);
    const int by = r2 / NBX;
    const int bx = r2 - by * NBX;
    const int X0 = bx * PXX, Y0 = by * PYY;
    const int tid = threadIdx.x;

    // ---- prefetch: issue all loads before anything depends on them ----
    float2 fv[NBATCH];
    float pv0[NBATCH], pv1[NBATCH], pv2[NBATCH];
    int pgx[NBATCH], pgy[NBATCH];
    bool pok[NBATCH];
#pragma unroll
    for (int t = 0; t < NBATCH; ++t) {
        int i = tid + t * THREADS;
        int wy = i / WINX;
        int wx = i - wy * WINX;
        int gx = X0 - RAD + wx;
        int gy = Y0 - RAD + wy;
        pok[t] = (i < NWIN) & (gx >= 0) & (gx < WW) & (gy >= 0) & (gy < HH);
        pgx[t] = gx; pgy[t] = gy;
        int cgx = min(max(gx, 0), WW - 1);
        int cgy = min(max(gy, 0), HH - 1);
        fv[t] = reinterpret_cast<const float2*>(flow)[(b * HH + cgy) * WW + cgx];
        int src = b * CC * PLANE + cgy * WW + cgx;
        pv0[t] = im0[src];
        pv1[t] = im0[src + PLANE];
        pv2[t] = im0[src + 2 * PLANE];
    }

    // zero LDS while loads are in flight (zero slots: wt=0, v=0 -> dot2 adds 0)
    uint4* lds4 = reinterpret_cast<uint4*>(lds);
    for (int i = tid; i < (LDS_DW + 3) / 4; i += THREADS)
        lds4[i] = make_uint4(0u, 0u, 0u, 0u);
    __syncthreads();

    // ---- phase A: bucket records, precompute 4 corner weight products ----
#pragma unroll
    for (int t = 0; t < NBATCH; ++t) {
        if (!pok[t]) continue;
        float2 f = fv[t];
        int gx = pgx[t], gy = pgy[t];
        bool reg = (f.x >= -(float)RAD) & (f.x < (float)RAD)
                 & (f.y >= -(float)RAD) & (f.y < (float)RAD);
        if (reg) {
            float x = (float)gx + f.x;       // same op order as reference
            float y = (float)gy + f.y;
            float x0f = floorf(x), y0f = floorf(y);
            int cx = (int)x0f - (X0 - 1);
            int cy = (int)y0f - (Y0 - 1);
            if (cx >= 0 && cx < CX && cy >= 0 && cy < CY) {
                float fx = x - x0f, fy = y - y0f;
                int cell = cy * CX + cx;
                unsigned int slot = atomicAdd(&CNT[cell], 1u);
                if (slot < DEPTH) {
                    float gx1 = 1.0f - fx, gy1 = 1.0f - fy;
                    unsigned short* cu =
                        (unsigned short*)((char*)lds + cell * CELLB);
                    // corners: c = dy*2+dx
                    cu[0 * 4 + slot]  = __half_as_ushort(__float2half(gx1 * gy1));
                    cu[1 * 4 + slot]  = __half_as_ushort(__float2half(fx  * gy1));
                    cu[2 * 4 + slot]  = __half_as_ushort(__float2half(gx1 * fy));
                    cu[3 * 4 + slot]  = __half_as_ushort(__float2half(fx  * fy));
                    cu[16 + slot]     = __half_as_ushort(__float2half(pv0[t]));
                    cu[20 + slot]     = __half_as_ushort(__float2half(pv1[t]));
                    cu[24 + slot]     = __half_as_ushort(__float2half(pv2[t]));
                } else {
                    // depth overflow (rare): owner-clipped replay (type 1)
                    unsigned int s2 = atomicAdd(LOVF, 1u);
                    if (s2 < OVF_CAP) {
                        float* q = ovf_rec + ((size_t)phys * OVF_CAP + s2) * 6;
                        q[0] = __int_as_float(b | (bx << 4) | (by << 9) | (1 << 16));
                        q[1] = x; q[2] = y;
                        q[3] = pv0[t]; q[4] = pv1[t]; q[5] = pv2[t];
                    }
                }
            }
        } else {
            int wx = gx - (X0 - RAD);
            int wy = gy - (Y0 - RAD);
            if (wx >= RAD && wx < RAD + PXX && wy >= RAD && wy < RAD + PYY) {
                // irregular flow, core-owned pixel: full-splat replay (type 0)
                unsigned int s2 = atomicAdd(LOVF, 1u);
                if (s2 < OVF_CAP) {
                    float* q = ovf_rec + ((size_t)phys * OVF_CAP + s2) * 6;
                    q[0] = __int_as_float(b | (bx << 4) | (by << 9));
                    q[1] = (float)gx + f.x; q[2] = (float)gy + f.y;
                    q[3] = pv0[t]; q[4] = pv1[t]; q[5] = pv2[t];
                }
            }
        }
    }
    __syncthreads();

    if (tid == 0) cnt_g[phys] = min(*LOVF, (unsigned int)OVF_CAP);

    // ---- phase B: 1 output/thread, 4 cells, 6 dot2 per cell, no weight math --
    const int lane = tid & 63;
    const int wrow = tid >> 6;                 // 0..7
    const int X = X0 + lane;
    const int Y = Y0 + wrow;

    float a0 = 0.f, a1 = 0.f, a2 = 0.f;

#pragma unroll
    for (int r = 0; r < 2; ++r) {              // cell row y0 = Y-1+r
        const int cy = wrow + r;
#pragma unroll
        for (int side = 0; side < 2; ++side) { // cell col x0 = X-1+side
            const int cell = cy * CX + lane + side;
            const char* cbase = (const char*)lds + cell * CELLB;
            // corner selector: dy = 1-r, dx = 1-side  ->  c = dy*2+dx
            const int c = (1 - r) * 2 + (1 - side);
            uint2 w  = *reinterpret_cast<const uint2*>(cbase + c * 8);
            uint2 v0 = *reinterpret_cast<const uint2*>(cbase + 32);
            uint2 v1 = *reinterpret_cast<const uint2*>(cbase + 40);
            uint2 v2 = *reinterpret_cast<const uint2*>(cbase + 48);
            a0 = DOT2(as_h2(w.x), as_h2(v0.x), a0);
            a0 = DOT2(as_h2(w.y), as_h2(v0.y), a0);
            a1 = DOT2(as_h2(w.x), as_h2(v1.x), a1);
            a1 = DOT2(as_h2(w.y), as_h2(v1.y), a1);
            a2 = DOT2(as_h2(w.x), as_h2(v2.x), a2);
            a2 = DOT2(as_h2(w.y), as_h2(v2.y), a2);
        }
    }

    size_t o = (size_t)(b * CC) * PLANE + (size_t)Y * WW + X;
    out[o] = a0;
    out[o + PLANE] = a1;
    out[o + 2 * PLANE] = a2;
}

// ---------------------------------------------------------------------------
// replay: scan per-block slabs. type0 = full splat, type1 = owner-clipped
// ---------------------------------------------------------------------------
__global__ __launch_bounds__(256) void fw_overflow(
    const unsigned int* __restrict__ cnt_g,
    const float* __restrict__ ovf_rec,
    float* __restrict__ out)
{
    int i = blockIdx.x * 256 + threadIdx.x;    // global slot id
    if (i >= NBLK * OVF_CAP) return;
    int blk  = i / OVF_CAP;
    int slot = i - blk * OVF_CAP;
    if ((unsigned int)slot >= cnt_g[blk]) return;

    const float* q = ovf_rec + (size_t)i * 6;
    unsigned int meta = __float_as_uint(q[0]);
    int b   = meta & 0xf;
    int rx0 = ((meta >> 4) & 0x1f) * PXX;
    int ry0 = ((meta >> 9) & 0x7f) * PYY;
    int typ = (meta >> 16) & 1;
    float x = q[1], y = q[2];
    float v0 = q[3], v1 = q[4], v2 = q[5];
    float x0f = floorf(x), y0f = floorf(y);
    int x0 = (int)x0f, y0 = (int)y0f;
    float wx1 = x - x0f, wx0 = 1.0f - wx1;
    float wy1 = y - y0f, wy0 = 1.0f - wy1;
#pragma unroll
    for (int dy = 0; dy < 2; ++dy) {
        int yi = y0 + dy;
        float wy = dy ? wy1 : wy0;
#pragma unroll
        for (int dx = 0; dx < 2; ++dx) {
            int xi = x0 + dx;
            bool valid = (xi >= 0) && (xi < WW) && (yi >= 0) && (yi < HH);
            if (typ)
                valid = valid && (xi >= rx0) && (xi < rx0 + PXX)
                              && (yi >= ry0) && (yi < ry0 + PYY);
            if (valid) {
                float wt = wy * (dx ? wx1 : wx0);
                int o = b * CC * PLANE + yi * WW + xi;
                unsafeAtomicAdd(&out[o],             wt * v0);
                unsafeAtomicAdd(&out[o + PLANE],     wt * v1);
                unsafeAtomicAdd(&out[o + 2 * PLANE], wt * v2);
            }
        }
    }
}

// ---------------------------------------------------------------------------
// safety fallback (tiny ws): naive global-atomic splat
// ---------------------------------------------------------------------------
__global__ __launch_bounds__(256) void fw_naive(
    const float* __restrict__ im0,
    const float* __restrict__ flow,
    float* __restrict__ out)
{
    int idx = blockIdx.x * blockDim.x + threadIdx.x;
    if (idx >= NPIX) return;
    int w = idx % WW;
    int t = idx / WW;
    int h = t % HH;
    int b = t / HH;
    float2 f = reinterpret_cast<const float2*>(flow)[idx];
    float x = (float)w + f.x, y = (float)h + f.y;
    float x0f = floorf(x), y0f = floorf(y);
    int x0 = (int)x0f, y0 = (int)y0f;
    float wx1 = x - x0f, wx0 = 1.0f - wx1;
    float wy1 = y - y0f, wy0 = 1.0f - wy1;
    int src = (b * CC * HH + h) * WW + w;
    float v0 = im0[src], v1 = im0[src + PLANE], v2 = im0[src + 2 * PLANE];
#pragma unroll
    for (int dy = 0; dy < 2; ++dy) {
        int yi = y0 + dy;
        if (yi < 0 || yi >= HH) continue;
        float wy = dy ? wy1 : wy0;
#pragma unroll
        for (int dx = 0; dx < 2; ++dx) {
            int xi = x0 + dx;
            if (xi < 0 || xi >= WW) continue;
            float wt = wy * (dx ? wx1 : wx0);
            int o = (b * CC) * PLANE + yi * WW + xi;
            unsafeAtomicAdd(&out[o],             wt * v0);
            unsafeAtomicAdd(&out[o + PLANE],     wt * v1);
            unsafeAtomicAdd(&out[o + 2 * PLANE], wt * v2);
        }
    }
}

extern "C" void kernel_launch(void* const* d_in, const int* in_sizes, int n_in,
                              void* d_out, int out_size, void* d_ws, size_t ws_size,
                              hipStream_t stream)
{
    const float* im0  = (const float*)d_in[0];
    const float* flow = (const float*)d_in[1];
    float* out = (float*)d_out;

    const size_t cnt_bytes = (size_t)NBLK * 4;                   // 57.6 KB
    const size_t rec_bytes = (size_t)NBLK * OVF_CAP * 24;        // ~11.1 MB
    if (ws_size >= cnt_bytes + rec_bytes) {
        unsigned int* cnt = (unsigned int*)d_ws;
        float* rec = (float*)((char*)d_ws + cnt_bytes);

        fw_gather<<<NBLK, THREADS, 0, stream>>>(im0, flow, out, cnt, rec);
        fw_overflow<<<(NBLK * OVF_CAP + 255) / 256, 256, 0, stream>>>(cnt, rec, out);
    } else {
        hipMemsetAsync(out, 0, (size_t)out_size * sizeof(float), stream);
        fw_naive<<<(NPIX + 255) / 256, 256, 0, stream>>>(im0, flow, out);
    }
}